// Round 4
// baseline (141.270 us; speedup 1.0000x reference)
//
#include <hip/hip_runtime.h>

#define OUT_F 11008
#define IN_F  4096
#define KHALF (IN_F / 2)     // K split across wave pairs
#define KSTEP 256            // k per step: lane*4, int4/float4 loads
#define NSTEP (KHALF / KSTEP)  // 8 steps

// Block = 256 threads = 4 waves. Waves (0,1) = K-halves of group g0,
// waves (2,3) = K-halves of group g1. Each group = 4 output rows.
// Grid = 11008/8 = 1376 blocks.
// Per step: issue x(t) [8x float4, L2-resident], then w(t+1) [4x int4,
// HBM/L3 stream, depth-1 prefetch -> full-step issue-to-use distance],
// then FMA(t). zero-point folded: out = s*(dot - zp*rowsum(x_b)) + bias.
__global__ __launch_bounds__(256, 4) void qlinear_kernel(
        const float* __restrict__ in, const int* __restrict__ qw,
        const int* __restrict__ zp, const float* __restrict__ scale,
        const float* __restrict__ bias, float* __restrict__ out) {
    const int lane  = threadIdx.x & 63;
    const int wave  = threadIdx.x >> 6;          // 0..3
    const int half  = wave & 1;                  // K-half
    const int group = blockIdx.x * 2 + (wave >> 1);
    const int row0  = group * 4;
    const int l4    = lane * 4;

    const int*   qp = qw + (size_t)row0 * IN_F + half * KHALF + l4;
    const float* xp = in + half * KHALF + l4;

    float acc[4][8];
    float asum[8];
    #pragma unroll
    for (int r = 0; r < 4; ++r)
        #pragma unroll
        for (int b = 0; b < 8; ++b) acc[r][b] = 0.f;
    #pragma unroll
    for (int b = 0; b < 8; ++b) asum[b] = 0.f;

    int4 wbuf[2][4];
    #pragma unroll
    for (int r = 0; r < 4; ++r)
        wbuf[0][r] = *reinterpret_cast<const int4*>(qp + r * IN_F);

    #pragma unroll
    for (int t = 0; t < NSTEP; ++t) {
        const int c = t & 1, n = c ^ 1;

        // x(t): L2-resident activations, issued first so the FMA's wait on
        // x retires w(t) (issued earlier) without draining w(t+1) (later).
        float4 x[8];
        #pragma unroll
        for (int b = 0; b < 8; ++b)
            x[b] = *reinterpret_cast<const float4*>(xp + b * IN_F + t * KSTEP);

        // w(t+1): depth-1 prefetch of the weight stream
        if (t + 1 < NSTEP) {
            #pragma unroll
            for (int r = 0; r < 4; ++r)
                wbuf[n][r] = *reinterpret_cast<const int4*>(qp + r * IN_F + (t + 1) * KSTEP);
        }

        float f[4][4];
        #pragma unroll
        for (int r = 0; r < 4; ++r) {
            f[r][0] = (float)wbuf[c][r].x;
            f[r][1] = (float)wbuf[c][r].y;
            f[r][2] = (float)wbuf[c][r].z;
            f[r][3] = (float)wbuf[c][r].w;
        }
        #pragma unroll
        for (int b = 0; b < 8; ++b) {
            const float4 xv = x[b];
            asum[b] += (xv.x + xv.y) + (xv.z + xv.w);
            #pragma unroll
            for (int r = 0; r < 4; ++r)
                acc[r][b] += f[r][0] * xv.x + f[r][1] * xv.y
                           + f[r][2] * xv.z + f[r][3] * xv.w;
        }
    }

    // --- cross-lane reduce of 32 dot-accumulators (register-halving tree):
    // after 5 levels lane l holds index (l&31) summed over its 32-lane half;
    // +xor32 -> full 64-lane sum on lanes 0..31.
    float v[32];
    #pragma unroll
    for (int r = 0; r < 4; ++r)
        #pragma unroll
        for (int b = 0; b < 8; ++b) v[r * 8 + b] = acc[r][b];

    #pragma unroll
    for (int k = 0; k < 5; ++k) {
        const bool hi = (lane >> k) & 1;
        const int  nn = 32 >> k;
        #pragma unroll
        for (int i = 0; i < 32; ++i) {
            if (i < nn / 2) {
                float keep = hi ? v[2 * i + 1] : v[2 * i];
                float send = hi ? v[2 * i]     : v[2 * i + 1];
                v[i] = keep + __shfl_xor(send, 1 << k);
            }
        }
    }
    const float total = v[0] + __shfl_xor(v[0], 32);   // this wave's K-half dot

    // --- reduce 8 row-sum accumulators -> full-wave rowsum of batch (lane&7)
    float s8[8];
    #pragma unroll
    for (int b = 0; b < 8; ++b) s8[b] = asum[b];
    #pragma unroll
    for (int k = 0; k < 3; ++k) {
        const bool hi = (lane >> k) & 1;
        const int  nn = 8 >> k;
        #pragma unroll
        for (int i = 0; i < 8; ++i) {
            if (i < nn / 2) {
                float keep = hi ? s8[2 * i + 1] : s8[2 * i];
                float send = hi ? s8[2 * i]     : s8[2 * i + 1];
                s8[i] = keep + __shfl_xor(send, 1 << k);
            }
        }
    }
    float S = s8[0];
    S += __shfl_xor(S, 8);
    S += __shfl_xor(S, 16);
    S += __shfl_xor(S, 32);   // K-half rowsum of batch (lane&7)

    // --- combine the two K-halves of each group via LDS ---
    __shared__ float ldsv[4][32];
    __shared__ float ldsS[4][8];
    if (lane < 32) ldsv[wave][lane] = total;
    if (lane < 8)  ldsS[wave][lane] = S;     // lane==b for lane<8
    __syncthreads();

    if (half == 0 && lane < 32) {
        const int r = lane >> 3;
        const int b = lane & 7;
        const int o = row0 + r;
        const float tot = total + ldsv[wave + 1][lane];
        const float Sf  = S + ldsS[wave + 1][b];
        out[(size_t)b * OUT_F + o] = scale[o] * (tot - (float)zp[o] * Sf) + bias[o];
    }
}

extern "C" void kernel_launch(void* const* d_in, const int* in_sizes, int n_in,
                              void* d_out, int out_size, void* d_ws, size_t ws_size,
                              hipStream_t stream) {
    const float* in    = (const float*)d_in[0];
    const int*   qw    = (const int*)  d_in[1];
    const int*   zp    = (const int*)  d_in[2];
    const float* scale = (const float*)d_in[3];
    const float* bias  = (const float*)d_in[4];
    float*       out   = (float*)d_out;

    const int blocks = OUT_F / 8;   // 1376 blocks: 2 groups x 2 K-halves each
    qlinear_kernel<<<blocks, 256, 0, stream>>>(in, qw, zp, scale, bias, out);
}

// Round 5
// 40.532 us; speedup vs baseline: 3.4854x; 3.4854x over previous
//
#include <hip/hip_runtime.h>

#define OUT_F 11008
#define IN_F  4096
#define KHALF (IN_F / 2)       // K split across wave pairs
#define KSTEP 256              // k per step: lane*4, int4/float4 loads
#define NSTEP (KHALF / KSTEP)  // 8 steps

// Block = 256 threads = 4 waves. Waves (0,1) = K-halves of group g0,
// waves (2,3) = K-halves of group g1. Each group = 4 output rows.
// Grid = 11008/8 = 1376 blocks -> 5504 waves = 21.5 waves/CU.
// Per step: x(t) [8x float4, L2-resident] issued first, then w(t+1)
// [4x int4, HBM/L3 stream, depth-1 prefetch]. The compiler's wait for
// x(t) is vmcnt(4), so w(t+1) stays in flight across FMA(t).
// zero-point folded: out = s*(dot - zp*rowsum(x_b)) + bias.
// NOTE: plain __launch_bounds__(256) — the ",4" min-occupancy variant
// made the allocator spill acc to scratch (R3: 200 MB scratch writes).
__global__ __launch_bounds__(256) void qlinear_kernel(
        const float* __restrict__ in, const int* __restrict__ qw,
        const int* __restrict__ zp, const float* __restrict__ scale,
        const float* __restrict__ bias, float* __restrict__ out) {
    const int lane  = threadIdx.x & 63;
    const int wave  = threadIdx.x >> 6;          // 0..3
    const int half  = wave & 1;                  // K-half
    const int group = blockIdx.x * 2 + (wave >> 1);
    const int row0  = group * 4;
    const int l4    = lane * 4;

    const int*   qp = qw + (size_t)row0 * IN_F + half * KHALF + l4;
    const float* xp = in + half * KHALF + l4;

    float acc[4][8];
    float asum[8];
    #pragma unroll
    for (int r = 0; r < 4; ++r)
        #pragma unroll
        for (int b = 0; b < 8; ++b) acc[r][b] = 0.f;
    #pragma unroll
    for (int b = 0; b < 8; ++b) asum[b] = 0.f;

    int4 wbuf[2][4];
    #pragma unroll
    for (int r = 0; r < 4; ++r)
        wbuf[0][r] = *reinterpret_cast<const int4*>(qp + r * IN_F);

    #pragma unroll
    for (int t = 0; t < NSTEP; ++t) {
        const int c = t & 1, n = c ^ 1;

        // x(t): issued first so the FMA's wait on x (vmcnt(4)) keeps the
        // w(t+1) prefetch in flight.
        float4 x[8];
        #pragma unroll
        for (int b = 0; b < 8; ++b)
            x[b] = *reinterpret_cast<const float4*>(xp + b * IN_F + t * KSTEP);

        // w(t+1): depth-1 prefetch of the weight stream
        if (t + 1 < NSTEP) {
            #pragma unroll
            for (int r = 0; r < 4; ++r)
                wbuf[n][r] = *reinterpret_cast<const int4*>(qp + r * IN_F + (t + 1) * KSTEP);
        }

        float f[4][4];
        #pragma unroll
        for (int r = 0; r < 4; ++r) {
            f[r][0] = (float)wbuf[c][r].x;
            f[r][1] = (float)wbuf[c][r].y;
            f[r][2] = (float)wbuf[c][r].z;
            f[r][3] = (float)wbuf[c][r].w;
        }
        #pragma unroll
        for (int b = 0; b < 8; ++b) {
            const float4 xv = x[b];
            asum[b] += (xv.x + xv.y) + (xv.z + xv.w);
            #pragma unroll
            for (int r = 0; r < 4; ++r)
                acc[r][b] += f[r][0] * xv.x + f[r][1] * xv.y
                           + f[r][2] * xv.z + f[r][3] * xv.w;
        }
    }

    // --- cross-lane reduce of 32 dot-accumulators (register-halving tree):
    // after 5 levels lane l holds index (l&31) summed over its 32-lane half;
    // +xor32 -> full 64-lane sum on lanes 0..31.
    float v[32];
    #pragma unroll
    for (int r = 0; r < 4; ++r)
        #pragma unroll
        for (int b = 0; b < 8; ++b) v[r * 8 + b] = acc[r][b];

    #pragma unroll
    for (int k = 0; k < 5; ++k) {
        const bool hi = (lane >> k) & 1;
        const int  nn = 32 >> k;
        #pragma unroll
        for (int i = 0; i < 32; ++i) {
            if (i < nn / 2) {
                float keep = hi ? v[2 * i + 1] : v[2 * i];
                float send = hi ? v[2 * i]     : v[2 * i + 1];
                v[i] = keep + __shfl_xor(send, 1 << k);
            }
        }
    }
    const float total = v[0] + __shfl_xor(v[0], 32);   // this wave's K-half dot

    // --- reduce 8 row-sum accumulators -> K-half rowsum of batch (lane&7)
    float s8[8];
    #pragma unroll
    for (int b = 0; b < 8; ++b) s8[b] = asum[b];
    #pragma unroll
    for (int k = 0; k < 3; ++k) {
        const bool hi = (lane >> k) & 1;
        const int  nn = 8 >> k;
        #pragma unroll
        for (int i = 0; i < 8; ++i) {
            if (i < nn / 2) {
                float keep = hi ? s8[2 * i + 1] : s8[2 * i];
                float send = hi ? s8[2 * i]     : s8[2 * i + 1];
                s8[i] = keep + __shfl_xor(send, 1 << k);
            }
        }
    }
    float S = s8[0];
    S += __shfl_xor(S, 8);
    S += __shfl_xor(S, 16);
    S += __shfl_xor(S, 32);   // K-half rowsum of batch (lane&7)

    // --- combine the two K-halves of each group via LDS ---
    __shared__ float ldsv[4][32];
    __shared__ float ldsS[4][8];
    if (lane < 32) ldsv[wave][lane] = total;
    if (lane < 8)  ldsS[wave][lane] = S;     // lane==b for lane<8
    __syncthreads();

    if (half == 0 && lane < 32) {
        const int r = lane >> 3;
        const int b = lane & 7;
        const int o = row0 + r;
        const float tot = total + ldsv[wave + 1][lane];
        const float Sf  = S + ldsS[wave + 1][b];
        out[(size_t)b * OUT_F + o] = scale[o] * (tot - (float)zp[o] * Sf) + bias[o];
    }
}

extern "C" void kernel_launch(void* const* d_in, const int* in_sizes, int n_in,
                              void* d_out, int out_size, void* d_ws, size_t ws_size,
                              hipStream_t stream) {
    const float* in    = (const float*)d_in[0];
    const int*   qw    = (const int*)  d_in[1];
    const int*   zp    = (const int*)  d_in[2];
    const float* scale = (const float*)d_in[3];
    const float* bias  = (const float*)d_in[4];
    float*       out   = (float*)d_out;

    const int blocks = OUT_F / 8;   // 1376 blocks: 2 groups x 2 K-halves each
    qlinear_kernel<<<blocks, 256, 0, stream>>>(in, qw, zp, scale, bias, out);
}